// Round 7
// baseline (142.160 us; speedup 1.0000x reference)
//
#include <hip/hip_runtime.h>
#include <hip/hip_fp16.h>
#include <math.h>

// Problem constants
#define NB 392      // n = b*oh*ow = 2*14*14
#define NI 288      // K*K*B = 9*32
#define NC 32       // C
#define NQ 16       // PSIZE
#define CQ 512      // NC*NQ
#define CH 544      // B*(PSIZE+1)
#define EPSV 1e-6f

// votes are fp8 e4m3 scaled by 32; scale folded into staged f16 weights
// (32 = 2^5, exact in f16 -> bitwise-identical products vs scaling after).
#define VSCALE 32.0f
#define VINV (1.0f / 32.0f)

// out layout (floats)
#define OFF_AOUT 200704       // NB*CQ
#define OFF_CAT  213248       // OFF_AOUT + NB*NC

#define RT_THREADS 512
#define RT_WAVES 8

// MEASUREMENT ROUND 7: routing_k launched with gridDim.y = 2. The y=1
// duplicate computes identically but writes outputs to a dead workspace
// region at +128 MiB (no races). The routing dispatch then runs ~2-3x its
// real duration -> exceeds the 43us poison fill and surfaces in the top-5
// WITH counters (VGPR_Count / Occupancy / VALUBusy / FETCH / conflicts).
// votes_k reverted to z=1 (round-6 measurement overhead removed).
#define DUP_OFF (128u << 20)

typedef _Float16 v4h __attribute__((ext_vector_type(4)));
typedef float v4f __attribute__((ext_vector_type(4)));
typedef float v2f __attribute__((ext_vector_type(2)));

// ---------------------------------------------------------------------------
// Gather from x via the unfold channel-major reinterpret.
__device__ __forceinline__ float gather_x(const float* __restrict__ x, int n, int j) {
    int c_idx = j / 9;
    int rem = j - c_idx * 9;
    int ki = rem / 3;
    int kj = rem - ki * 3;
    int b_ = n / 196;
    int rest = n - b_ * 196;
    int yy = rest / 14;
    int xx = rest - yy * 14;
    int iy = yy + ki - 1;
    int ix = xx + kj - 1;
    float v = 0.f;
    if ((unsigned)iy < 14u && (unsigned)ix < 14u)
        v = x[((b_ * 14 + iy) * 14 + ix) * CH + c_idx];
    return v;
}

// ---------------------------------------------------------------------------
// votes via swapped-operand mfma 16x16x16 f16 (round-3 structure, verified
// 22 us single-pass; WRITE 57.8 MB, VALUBusy 33%, MfmaUtil 6.7%).
__global__ __launch_bounds__(256) void votes_k(const float* __restrict__ x,
                                               const float* __restrict__ wts,
                                               uchar* __restrict__ votes) {
    __shared__ _Float16 wlds[8192];     // 16 KB swizzled f16 weights (x32)
    __shared__ uint tile[64 * 36];      // 9 KB, pitch 36 dwords (144 B)
    int mtt = blockIdx.x;         // 0..6
    int i = blockIdx.y;           // 0..287
    int t = threadIdx.x;
    int wv = t >> 6;
    int l = t & 63;
    int col = l & 15;
    int quad = l >> 4;

    // ---- stage wts[i] -> LDS (f16, x32, transposed, swizzled) ----
    const float* wsrc = wts + (size_t)i * 8192;
#pragma unroll
    for (int k = 0; k < 8; ++k) {
        int f0 = k * 1024 + t * 4;
        float4 w4 = *(const float4*)(wsrc + f0);
        int ct = f0 >> 8;
        int p = (f0 >> 4) & 15;
        int qd = p >> 2;
        int kk = p & 3;
        int q0 = f0 & 15;
        int s = (ct * 4 + qd) & 15;
        int base = ct * 256 + qd * 64 + kk;
        wlds[base + (((q0 + 0) ^ s) << 2)] = (_Float16)(w4.x * VSCALE);
        wlds[base + (((q0 + 1) ^ s) << 2)] = (_Float16)(w4.y * VSCALE);
        wlds[base + (((q0 + 2) ^ s) << 2)] = (_Float16)(w4.z * VSCALE);
        wlds[base + (((q0 + 3) ^ s) << 2)] = (_Float16)(w4.w * VSCALE);
    }

    // A-side p-frag: gather 4 p-values from x in-lane (n_row = col-mapped)
    int n_row = mtt * 64 + wv * 16 + col;
    v4h av = {};
    if (n_row < NB) {
        int jb = (i >> 5) * CH + (i & 31) * 16 + quad * 4;
#pragma unroll
        for (int kk = 0; kk < 4; ++kk)
            av[kk] = (_Float16)gather_x(x, n_row, jb + kk);
    }
    __syncthreads();

    const uchar* tileb = (const uchar*)tile;

    for (int ch = 0; ch < 4; ++ch) {
#pragma unroll
        for (int c8 = 0; c8 < 8; ++c8) {
            int ct = ch * 8 + c8;
            // bv: one conflict-free ds_read_b64 (weights pre-scaled x32)
            v4h bv = *(const v4h*)&wlds[ct * 256 + quad * 64 +
                                        ((col ^ ((ct * 4 + quad) & 15)) << 2)];
            v4f acc = {0.f, 0.f, 0.f, 0.f};
            acc = __builtin_amdgcn_mfma_f32_16x16x16f16(bv, av, acc, 0, 0, 0);
            // lane holds votes[n=...+col][cq = ct*16 + quad*4 + 0..3]
            uint u = __builtin_amdgcn_cvt_pk_fp8_f32(acc[0], acc[1], 0, false);
            u = __builtin_amdgcn_cvt_pk_fp8_f32(acc[2], acc[3], u, true);
            tile[(wv * 16 + col) * 36 + c8 * 4 + quad] = u;
        }
        __syncthreads();
        // 64 rows x 8 uint4 = 512 uint4; 2 steps; 8 lanes store a row's 128 B.
#pragma unroll
        for (int k = 0; k < 2; ++k) {
            int idx = k * 256 + t;
            int row = idx >> 3;
            int off = idx & 7;
            int n_out = mtt * 64 + row;
            if (n_out < NB) {
                uint4 d = *(const uint4*)&tileb[row * 144 + off * 16];
                *(uint4*)(votes + (((size_t)n_out * NI + i) << 9) + ch * 128 + off * 16) = d;
            }
        }
        __syncthreads();
    }
}

// ---------------------------------------------------------------------------
// Fused dynamic routing — round-0/3 best-measured form, code UNTOUCHED except
// the dup-output base select (measurement; y=1 writes to dead region).
__global__ __launch_bounds__(RT_THREADS) void routing_k(const uchar* __restrict__ votes,
                                                        const float* __restrict__ x,
                                                        float* __restrict__ out,
                                                        float* __restrict__ out_dead) {
    __shared__ float afs[NI];
    __shared__ float sred[RT_WAVES * CQ];   // 16 KB, [group][q*32+c]
    __shared__ float vj[CQ];                // [q*32+c]
    __shared__ float aout_s[NC];

    int n = blockIdx.x;
    int t = threadIdx.x;
    int wv = t >> 6;      // 0..7
    int l = t & 63;
    int c = l & 31;
    int g = l >> 5;

    // y=1 duplicate writes to the dead region (measurement only)
    float* ob = (blockIdx.y == 0) ? out : out_dead;

    if (t < NI) {
        int j = (t >> 5) * CH + 512 + (t & 31);
        float v = gather_x(x, n, j);
        float a = fminf(fmaxf(v, 1e-4f), 1.0f);
        afs[t] = a / (a + EPSV);
    }
    __syncthreads();

    const uchar* vb = votes + (size_t)n * NI * 512;
    float vjr[16];    // cumulative vj, PRE-SCALED by 1/32
    float sreg[16];

#define VROW(S) (((const uint4*)(vb + ((size_t)(((((S) << 3) + wv) << 1) + g) << 9)))[c])

    for (int iter = 0; iter < 3; ++iter) {
#pragma unroll
        for (int q = 0; q < 16; ++q) sreg[q] = 0.f;

        uint4 f0 = VROW(0), f1 = VROW(1), f2 = VROW(2), f3 = VROW(3);

#pragma clang loop unroll_count(2)
        for (int s = 0; s < 18; ++s) {
            int i = ((s << 3) + wv) * 2 + g;
            uint4 cur = f0;
            f0 = f1; f1 = f2; f2 = f3;
            if (s + 4 < 18) f3 = VROW(s + 4);

            float vt[16];   // raw fp8-decoded (x32-scaled votes)
            {
                v2f p;
                p = __builtin_amdgcn_cvt_pk_f32_fp8(cur.x, false); vt[0] = p[0];  vt[1] = p[1];
                p = __builtin_amdgcn_cvt_pk_f32_fp8(cur.x, true);  vt[2] = p[0];  vt[3] = p[1];
                p = __builtin_amdgcn_cvt_pk_f32_fp8(cur.y, false); vt[4] = p[0];  vt[5] = p[1];
                p = __builtin_amdgcn_cvt_pk_f32_fp8(cur.y, true);  vt[6] = p[0];  vt[7] = p[1];
                p = __builtin_amdgcn_cvt_pk_f32_fp8(cur.z, false); vt[8] = p[0];  vt[9] = p[1];
                p = __builtin_amdgcn_cvt_pk_f32_fp8(cur.z, true);  vt[10] = p[0]; vt[11] = p[1];
                p = __builtin_amdgcn_cvt_pk_f32_fp8(cur.w, false); vt[12] = p[0]; vt[13] = p[1];
                p = __builtin_amdgcn_cvt_pk_f32_fp8(cur.w, true);  vt[14] = p[0]; vt[15] = p[1];
            }
            float cij;
            if (iter == 0) {
                cij = afs[i] * (1.0f / 32.0f);
            } else {
                float ah = 0.f;   // vt(raw) . vjr(pre-scaled) == true dot
#pragma unroll
                for (int q = 0; q < 16; ++q) ah += vt[q] * vjr[q];
                float e = __expf(ah);
                float ssum = e;
                ssum += __shfl_xor(ssum, 1);
                ssum += __shfl_xor(ssum, 2);
                ssum += __shfl_xor(ssum, 4);
                ssum += __shfl_xor(ssum, 8);
                ssum += __shfl_xor(ssum, 16);
                cij = e * __builtin_amdgcn_rcpf(ssum) * afs[i];
            }
#pragma unroll
            for (int q = 0; q < 16; ++q) sreg[q] += cij * vt[q];
        }

        // fold g-halves, write 8 partial groups (layout [q*32+c]: bank==c)
#pragma unroll
        for (int q = 0; q < 16; ++q) sreg[q] += __shfl_xor(sreg[q], 32);
        if (g == 0) {
            float* sw = &sred[wv * CQ + c];
#pragma unroll
            for (int q = 0; q < 16; ++q) sw[q * 32] = sreg[q];
        }
        __syncthreads();
        {
            float ssum = 0.f;   // 512 threads == CQ columns
#pragma unroll
            for (int k = 0; k < RT_WAVES; ++k) ssum += sred[k * CQ + t];
            sred[t] = ssum * VINV;   // descale the x32 fp8 encoding ONCE
        }
        __syncthreads();

        // squash (threads 0..31, one c each; element (c,q) at sred[q*32+c])
        if (t < NC) {
            float s2 = 0.f;
#pragma unroll
            for (int q = 0; q < 16; ++q) {
                float s = sred[q * 32 + t];
                s2 += s * s;
            }
            float f = (s2 / (1.f + s2)) / sqrtf(s2 + EPSV);
            float vn2 = 0.f;
#pragma unroll
            for (int q = 0; q < 16; ++q) {
                float v = f * sred[q * 32 + t];
                vj[q * 32 + t] = v;
                vn2 += v * v;
            }
            if (iter == 2) {
                float ao = sqrtf(vn2 + EPSV);
                ao = fminf(fmaxf(ao, 1e-4f), 1.f - 1e-4f);
                aout_s[t] = ao;
            }
        }
        __syncthreads();
        if (iter < 2) {
#pragma unroll
            for (int q = 0; q < 16; ++q) {
                float v = vj[q * 32 + c] * VINV;   // pre-scale for the raw dot
                vjr[q] = (iter == 0) ? v : vjr[q] + v;
            }
        }
    }

    // outputs: p_out, a_out, concat(out).  canonical idx t: c=t>>4, q=t&15
    {
        float v = vj[(t & 15) * 32 + (t >> 4)];
        ob[(size_t)n * CQ + t] = v;
        ob[OFF_CAT + (size_t)n * 544 + t] = v;
    }
    if (t < NC) {
        float ao = aout_s[t];
        ob[OFF_AOUT + n * 32 + t] = ao;
        ob[OFF_CAT + (size_t)n * 544 + 512 + t] = ao;
    }
}

// ---------------------------------------------------------------------------
extern "C" void kernel_launch(void* const* d_in, const int* in_sizes, int n_in,
                              void* d_out, int out_size, void* d_ws, size_t ws_size,
                              hipStream_t stream) {
    const float* x = (const float*)d_in[0];
    const float* wts = (const float*)d_in[1];
    float* out = (float*)d_out;
    uchar* votes = (uchar*)d_ws;   // 57.8 MB fp8
    float* out_dead = (float*)((uchar*)d_ws + DUP_OFF);   // measurement sink

    hipLaunchKernelGGL(votes_k, dim3(7, NI), dim3(256), 0, stream,
                       x, wts, votes);
    // gridDim.y = 2: measurement round (see DUP_OFF comment).
    hipLaunchKernelGGL(routing_k, dim3(NB, 2), dim3(RT_THREADS), 0, stream,
                       votes, x, out, out_dead);
}

// Round 8
// 113.108 us; speedup vs baseline: 1.2569x; 1.2569x over previous
//
#include <hip/hip_runtime.h>
#include <hip/hip_fp16.h>
#include <math.h>

// Problem constants
#define NB 392      // n = b*oh*ow = 2*14*14
#define NI 288      // K*K*B = 9*32
#define NC 32       // C
#define NQ 16       // PSIZE
#define CQ 512      // NC*NQ
#define CH 544      // B*(PSIZE+1)
#define EPSV 1e-6f

// votes are fp8 e4m3 scaled by 32; scale folded into staged f16 weights
// (32 = 2^5, exact in f16 -> bitwise-identical products vs scaling after).
#define VSCALE 32.0f
#define VINV (1.0f / 32.0f)

// out layout (floats)
#define OFF_AOUT 200704       // NB*CQ
#define OFF_CAT  213248       // OFF_AOUT + NB*NC

#define RT_THREADS 512
#define RT_WAVES 8

typedef _Float16 v4h __attribute__((ext_vector_type(4)));
typedef float v4f __attribute__((ext_vector_type(4)));
typedef float v2f __attribute__((ext_vector_type(2)));

// dual-f32 FMA (VOP3P). hipcc does not auto-generate it from scalar code;
// round-7 counters show routing is VALU-issue-bound (VALUBusy 44%, HBM 20%,
// MfmaUtil 0) -> halving the FMA instruction count is the lever.
__device__ __forceinline__ v2f pk_fma(v2f a, v2f b, v2f c) {
    v2f d;
    asm volatile("v_pk_fma_f32 %0, %1, %2, %3" : "=v"(d) : "v"(a), "v"(b), "v"(c));
    return d;
}

// ---------------------------------------------------------------------------
// Gather from x via the unfold channel-major reinterpret.
__device__ __forceinline__ float gather_x(const float* __restrict__ x, int n, int j) {
    int c_idx = j / 9;
    int rem = j - c_idx * 9;
    int ki = rem / 3;
    int kj = rem - ki * 3;
    int b_ = n / 196;
    int rest = n - b_ * 196;
    int yy = rest / 14;
    int xx = rest - yy * 14;
    int iy = yy + ki - 1;
    int ix = xx + kj - 1;
    float v = 0.f;
    if ((unsigned)iy < 14u && (unsigned)ix < 14u)
        v = x[((b_ * 14 + iy) * 14 + ix) * CH + c_idx];
    return v;
}

// ---------------------------------------------------------------------------
// votes via swapped-operand mfma 16x16x16 f16 (round-3 structure, measured
// ~22 us single-pass; WRITE 57.8 MB (floor ~9 us), VALUBusy 33%). Untouched.
__global__ __launch_bounds__(256) void votes_k(const float* __restrict__ x,
                                               const float* __restrict__ wts,
                                               uchar* __restrict__ votes) {
    __shared__ _Float16 wlds[8192];     // 16 KB swizzled f16 weights (x32)
    __shared__ uint tile[64 * 36];      // 9 KB, pitch 36 dwords (144 B)
    int mtt = blockIdx.x;         // 0..6
    int i = blockIdx.y;           // 0..287
    int t = threadIdx.x;
    int wv = t >> 6;
    int l = t & 63;
    int col = l & 15;
    int quad = l >> 4;

    // ---- stage wts[i] -> LDS (f16, x32, transposed, swizzled) ----
    const float* wsrc = wts + (size_t)i * 8192;
#pragma unroll
    for (int k = 0; k < 8; ++k) {
        int f0 = k * 1024 + t * 4;
        float4 w4 = *(const float4*)(wsrc + f0);
        int ct = f0 >> 8;
        int p = (f0 >> 4) & 15;
        int qd = p >> 2;
        int kk = p & 3;
        int q0 = f0 & 15;
        int s = (ct * 4 + qd) & 15;
        int base = ct * 256 + qd * 64 + kk;
        wlds[base + (((q0 + 0) ^ s) << 2)] = (_Float16)(w4.x * VSCALE);
        wlds[base + (((q0 + 1) ^ s) << 2)] = (_Float16)(w4.y * VSCALE);
        wlds[base + (((q0 + 2) ^ s) << 2)] = (_Float16)(w4.z * VSCALE);
        wlds[base + (((q0 + 3) ^ s) << 2)] = (_Float16)(w4.w * VSCALE);
    }

    // A-side p-frag: gather 4 p-values from x in-lane (n_row = col-mapped)
    int n_row = mtt * 64 + wv * 16 + col;
    v4h av = {};
    if (n_row < NB) {
        int jb = (i >> 5) * CH + (i & 31) * 16 + quad * 4;
#pragma unroll
        for (int kk = 0; kk < 4; ++kk)
            av[kk] = (_Float16)gather_x(x, n_row, jb + kk);
    }
    __syncthreads();

    const uchar* tileb = (const uchar*)tile;

    for (int ch = 0; ch < 4; ++ch) {
#pragma unroll
        for (int c8 = 0; c8 < 8; ++c8) {
            int ct = ch * 8 + c8;
            // bv: one conflict-free ds_read_b64 (weights pre-scaled x32)
            v4h bv = *(const v4h*)&wlds[ct * 256 + quad * 64 +
                                        ((col ^ ((ct * 4 + quad) & 15)) << 2)];
            v4f acc = {0.f, 0.f, 0.f, 0.f};
            acc = __builtin_amdgcn_mfma_f32_16x16x16f16(bv, av, acc, 0, 0, 0);
            // lane holds votes[n=...+col][cq = ct*16 + quad*4 + 0..3]
            uint u = __builtin_amdgcn_cvt_pk_fp8_f32(acc[0], acc[1], 0, false);
            u = __builtin_amdgcn_cvt_pk_fp8_f32(acc[2], acc[3], u, true);
            tile[(wv * 16 + col) * 36 + c8 * 4 + quad] = u;
        }
        __syncthreads();
        // 64 rows x 8 uint4 = 512 uint4; 2 steps; 8 lanes store a row's 128 B.
#pragma unroll
        for (int k = 0; k < 2; ++k) {
            int idx = k * 256 + t;
            int row = idx >> 3;
            int off = idx & 7;
            int n_out = mtt * 64 + row;
            if (n_out < NB) {
                uint4 d = *(const uint4*)&tileb[row * 144 + off * 16];
                *(uint4*)(votes + (((size_t)n_out * NI + i) << 9) + ch * 128 + off * 16) = d;
            }
        }
        __syncthreads();
    }
}

// ---------------------------------------------------------------------------
// Fused dynamic routing — round-0 structure, inner math rewritten in PACKED
// f32 (v_pk_fma_f32): agreement dot 16 FMA -> 8 pk_fma + 1 add; s_j
// accumulate 16 FMA -> 8 pk_fma. fp8 decode already yields float2 pairs.
// Per-element s_j accumulation order unchanged; the ah dot becomes two
// 8-chains + final add (pairwise, if anything more accurate).
__global__ __launch_bounds__(RT_THREADS) void routing_k(const uchar* __restrict__ votes,
                                                        const float* __restrict__ x,
                                                        float* __restrict__ out) {
    __shared__ float afs[NI];
    __shared__ float sred[RT_WAVES * CQ];   // 16 KB, [group][q*32+c]
    __shared__ float vj[CQ];                // [q*32+c]
    __shared__ float aout_s[NC];

    int n = blockIdx.x;
    int t = threadIdx.x;
    int wv = t >> 6;      // 0..7
    int l = t & 63;
    int c = l & 31;
    int g = l >> 5;

    if (t < NI) {
        int j = (t >> 5) * CH + 512 + (t & 31);
        float v = gather_x(x, n, j);
        float a = fminf(fmaxf(v, 1e-4f), 1.0f);
        afs[t] = a / (a + EPSV);
    }
    __syncthreads();

    const uchar* vb = votes + (size_t)n * NI * 512;
    v2f vjr2[8];    // cumulative vj pairs, PRE-SCALED by 1/32
    v2f sreg2[8];

#define VROW(S) (((const uint4*)(vb + ((size_t)(((((S) << 3) + wv) << 1) + g) << 9)))[c])

    for (int iter = 0; iter < 3; ++iter) {
#pragma unroll
        for (int j = 0; j < 8; ++j) sreg2[j] = (v2f){0.f, 0.f};

        uint4 f0 = VROW(0), f1 = VROW(1), f2 = VROW(2), f3 = VROW(3);

#pragma clang loop unroll_count(2)
        for (int s = 0; s < 18; ++s) {
            int i = ((s << 3) + wv) * 2 + g;
            uint4 cur = f0;
            f0 = f1; f1 = f2; f2 = f3;
            if (s + 4 < 18) f3 = VROW(s + 4);

            v2f vt2[8];   // raw fp8-decoded pairs (x32-scaled votes)
            vt2[0] = __builtin_amdgcn_cvt_pk_f32_fp8(cur.x, false);
            vt2[1] = __builtin_amdgcn_cvt_pk_f32_fp8(cur.x, true);
            vt2[2] = __builtin_amdgcn_cvt_pk_f32_fp8(cur.y, false);
            vt2[3] = __builtin_amdgcn_cvt_pk_f32_fp8(cur.y, true);
            vt2[4] = __builtin_amdgcn_cvt_pk_f32_fp8(cur.z, false);
            vt2[5] = __builtin_amdgcn_cvt_pk_f32_fp8(cur.z, true);
            vt2[6] = __builtin_amdgcn_cvt_pk_f32_fp8(cur.w, false);
            vt2[7] = __builtin_amdgcn_cvt_pk_f32_fp8(cur.w, true);

            float cij;
            if (iter == 0) {
                cij = afs[i] * (1.0f / 32.0f);
            } else {
                v2f acc2 = {0.f, 0.f};   // vt(raw) . vjr(pre-scaled) == true dot
#pragma unroll
                for (int j = 0; j < 8; ++j) acc2 = pk_fma(vt2[j], vjr2[j], acc2);
                float ah = acc2[0] + acc2[1];
                float e = __expf(ah);
                float ssum = e;
                ssum += __shfl_xor(ssum, 1);
                ssum += __shfl_xor(ssum, 2);
                ssum += __shfl_xor(ssum, 4);
                ssum += __shfl_xor(ssum, 8);
                ssum += __shfl_xor(ssum, 16);
                cij = e * __builtin_amdgcn_rcpf(ssum) * afs[i];
            }
            v2f cij2 = {cij, cij};
#pragma unroll
            for (int j = 0; j < 8; ++j) sreg2[j] = pk_fma(cij2, vt2[j], sreg2[j]);
        }

        // fold g-halves, write 8 partial groups (layout [q*32+c]: bank==c)
#pragma unroll
        for (int j = 0; j < 8; ++j) {
            v2f o;
            o[0] = __shfl_xor(sreg2[j][0], 32);
            o[1] = __shfl_xor(sreg2[j][1], 32);
            sreg2[j] += o;
        }
        if (g == 0) {
            float* sw = &sred[wv * CQ + c];
#pragma unroll
            for (int j = 0; j < 8; ++j) {
                sw[(2 * j) * 32] = sreg2[j][0];
                sw[(2 * j + 1) * 32] = sreg2[j][1];
            }
        }
        __syncthreads();
        {
            float ssum = 0.f;   // 512 threads == CQ columns
#pragma unroll
            for (int k = 0; k < RT_WAVES; ++k) ssum += sred[k * CQ + t];
            sred[t] = ssum * VINV;   // descale the x32 fp8 encoding ONCE
        }
        __syncthreads();

        // squash (threads 0..31, one c each; element (c,q) at sred[q*32+c])
        if (t < NC) {
            float s2 = 0.f;
#pragma unroll
            for (int q = 0; q < 16; ++q) {
                float s = sred[q * 32 + t];
                s2 += s * s;
            }
            float f = (s2 / (1.f + s2)) / sqrtf(s2 + EPSV);
            float vn2 = 0.f;
#pragma unroll
            for (int q = 0; q < 16; ++q) {
                float v = f * sred[q * 32 + t];
                vj[q * 32 + t] = v;
                vn2 += v * v;
            }
            if (iter == 2) {
                float ao = sqrtf(vn2 + EPSV);
                ao = fminf(fmaxf(ao, 1e-4f), 1.f - 1e-4f);
                aout_s[t] = ao;
            }
        }
        __syncthreads();
        if (iter < 2) {
#pragma unroll
            for (int j = 0; j < 8; ++j) {
                v2f nv;
                nv[0] = vj[(2 * j) * 32 + c] * VINV;       // pre-scale for raw dot
                nv[1] = vj[(2 * j + 1) * 32 + c] * VINV;
                vjr2[j] = (iter == 0) ? nv : vjr2[j] + nv;
            }
        }
    }

    // outputs: p_out, a_out, concat(out).  canonical idx t: c=t>>4, q=t&15
    {
        float v = vj[(t & 15) * 32 + (t >> 4)];
        out[(size_t)n * CQ + t] = v;
        out[OFF_CAT + (size_t)n * 544 + t] = v;
    }
    if (t < NC) {
        float ao = aout_s[t];
        out[OFF_AOUT + n * 32 + t] = ao;
        out[OFF_CAT + (size_t)n * 544 + 512 + t] = ao;
    }
}

// ---------------------------------------------------------------------------
extern "C" void kernel_launch(void* const* d_in, const int* in_sizes, int n_in,
                              void* d_out, int out_size, void* d_ws, size_t ws_size,
                              hipStream_t stream) {
    const float* x = (const float*)d_in[0];
    const float* wts = (const float*)d_in[1];
    float* out = (float*)d_out;
    uchar* votes = (uchar*)d_ws;   // 57.8 MB fp8

    hipLaunchKernelGGL(votes_k, dim3(7, NI), dim3(256), 0, stream,
                       x, wts, votes);
    hipLaunchKernelGGL(routing_k, dim3(NB), dim3(RT_THREADS), 0, stream,
                       votes, x, out);
}